// Round 5
// baseline (590.541 us; speedup 1.0000x reference)
//
#include <hip/hip_runtime.h>
#include <math.h>

// ---------------------------------------------------------------------------
// ForgettingAttentionLayer, MI355X bf16-MFMA pipeline.  B=2 T=2048 C=2048 H=16 D=128.
// R4: flash v3 = counted-vmcnt depth-2 pipeline (3 buffers, raw s_barrier,
//     vmcnt(2) never 0 in loop), cum staged to LDS (keeps loop VMEM = DMA only),
//     T13 defer-rescale.  gemm_bt: XCD-aware bijective block swizzle (T1).
// ---------------------------------------------------------------------------

typedef __attribute__((ext_vector_type(8))) short  shortx8;
typedef __attribute__((ext_vector_type(4))) float  floatx4;

#define DEV __device__ __forceinline__

DEV unsigned short f2bf(float f) {                 // fp32 -> bf16 RNE
    unsigned int u = __builtin_bit_cast(unsigned int, f);
    u += 0x7FFFu + ((u >> 16) & 1u);
    return (unsigned short)(u >> 16);
}
DEV float bf2f(unsigned short s) {
    unsigned int u = ((unsigned int)s) << 16;
    return __builtin_bit_cast(float, u);
}
DEV void async16(void* lds, const void* g) {       // 16B global->LDS DMA
    __builtin_amdgcn_global_load_lds(
        (const __attribute__((address_space(1))) unsigned int*)g,
        (__attribute__((address_space(3))) unsigned int*)lds, 16, 0, 0);
}

// ---------------------------------------------------------------------------
__global__ void cvt_bf16(const float* __restrict__ in, unsigned short* __restrict__ out, int n8) {
    int i = blockIdx.x * 256 + threadIdx.x;
    if (i >= n8) return;
    float4 u = ((const float4*)in)[2 * i];
    float4 v = ((const float4*)in)[2 * i + 1];
    shortx8 r;
    r[0] = (short)f2bf(u.x); r[1] = (short)f2bf(u.y); r[2] = (short)f2bf(u.z); r[3] = (short)f2bf(u.w);
    r[4] = (short)f2bf(v.x); r[5] = (short)f2bf(v.y); r[6] = (short)f2bf(v.z); r[7] = (short)f2bf(v.w);
    *(shortx8*)(out + (size_t)i * 8) = r;
}

// Wcat: rows 0-15 Wsq, 16-31 Wsk, 32-47 Wsv, 48-63 Wf, 64-127 zero. (128,2048) bf16
__global__ void build_wcat(const float* __restrict__ Wsq, const float* __restrict__ Wsk,
                           const float* __restrict__ Wsv, const float* __restrict__ Wf,
                           unsigned short* __restrict__ out) {
    int i = blockIdx.x * 256 + threadIdx.x;
    int c8 = i & 255;
    int row = i >> 8;
    const float* src = nullptr;
    if      (row < 16) src = Wsq + (size_t)row * 2048;
    else if (row < 32) src = Wsk + (size_t)(row - 16) * 2048;
    else if (row < 48) src = Wsv + (size_t)(row - 32) * 2048;
    else if (row < 64) src = Wf  + (size_t)(row - 48) * 2048;
    shortx8 r = (shortx8){0,0,0,0,0,0,0,0};
    if (src) {
#pragma unroll
        for (int q = 0; q < 8; ++q) r[q] = (short)f2bf(src[c8 * 8 + q]);
    }
    *(shortx8*)(out + (size_t)i * 8) = r;
}

// ---------------------------------------------------------------------------
// C(M,N) = A(M,K) @ B(N,K)^T ; m97 structure + XCD-aware block swizzle (T1).
// All launches have nwg % 8 == 0 (bijective remap).
// ---------------------------------------------------------------------------
template <typename OutT>
__global__ __launch_bounds__(256)
void gemm_bt(const unsigned short* __restrict__ A, const unsigned short* __restrict__ B,
             OutT* __restrict__ C, int M, int N, int K) {
    __shared__ __align__(16) unsigned short As[2][128 * 32];
    __shared__ __align__(16) unsigned short Bs[2][128 * 32];
    const int tid  = threadIdx.x;
    const int lane = tid & 63;
    const int w    = tid >> 6;
    // XCD swizzle: consecutive work-ids land on the same XCD chunk (share B-panel)
    const int nwg  = gridDim.x * gridDim.y;
    const int bid0 = blockIdx.y * gridDim.x + blockIdx.x;
    const int bids = (bid0 & 7) * (nwg >> 3) + (bid0 >> 3);
    const int m0   = (bids % gridDim.x) * 128;
    const int n0   = (bids / gridDim.x) * 128;
    const int wr   = (w >> 1) * 64;
    const int wc   = (w & 1) * 64;
    const int l15  = lane & 15, lg = lane >> 4;
    const int nk   = K >> 5;
    const int c0   = w * 64 + lane;

    floatx4 acc[4][4];
#pragma unroll
    for (int i = 0; i < 4; ++i)
#pragma unroll
        for (int j = 0; j < 4; ++j) acc[i][j] = (floatx4){0.f, 0.f, 0.f, 0.f};

#pragma unroll
    for (int t = 0; t < 2; ++t) {
        int c = t * 256 + c0;
        int row = c >> 2, seg = c & 3;
        async16(&As[0][(t * 256 + w * 64) * 8], A + (size_t)(m0 + row) * K + seg * 8);
        async16(&Bs[0][(t * 256 + w * 64) * 8], B + (size_t)(n0 + row) * K + seg * 8);
    }
    int cur = 0;
    for (int kt = 0; kt < nk; ++kt) {
        __syncthreads();
        if (kt + 1 < nk) {
#pragma unroll
            for (int t = 0; t < 2; ++t) {
                int c = t * 256 + c0;
                int row = c >> 2, seg = c & 3;
                async16(&As[cur ^ 1][(t * 256 + w * 64) * 8],
                        A + (size_t)(m0 + row) * K + (kt + 1) * 32 + seg * 8);
                async16(&Bs[cur ^ 1][(t * 256 + w * 64) * 8],
                        B + (size_t)(n0 + row) * K + (kt + 1) * 32 + seg * 8);
            }
        }
        shortx8 af[4], bfr[4];
#pragma unroll
        for (int i = 0; i < 4; ++i) {
            af[i]  = *(const shortx8*)&As[cur][(wr + i * 16 + l15) * 32 + 8 * lg];
            bfr[i] = *(const shortx8*)&Bs[cur][(wc + i * 16 + l15) * 32 + 8 * lg];
        }
#pragma unroll
        for (int i = 0; i < 4; ++i)
#pragma unroll
            for (int j = 0; j < 4; ++j)
                acc[i][j] = __builtin_amdgcn_mfma_f32_16x16x32_bf16(af[i], bfr[j], acc[i][j], 0, 0, 0);
        cur ^= 1;
    }
#pragma unroll
    for (int i = 0; i < 4; ++i)
#pragma unroll
        for (int j = 0; j < 4; ++j)
#pragma unroll
            for (int r = 0; r < 4; ++r) {
                int row = m0 + wr + i * 16 + 4 * lg + r;
                int col = n0 + wc + j * 16 + l15;
                float v = acc[i][j][r];
                if constexpr (sizeof(OutT) == 2) C[(size_t)row * N + col] = (OutT)f2bf(v);
                else                             C[(size_t)row * N + col] = v;
            }
}

// ---------------------------------------------------------------------------
__global__ void cumsum_logf(const float* __restrict__ glog, const float* __restrict__ bfv,
                            float* __restrict__ cum) {
    __shared__ float sums[256];
    const int bh = blockIdx.x, b = bh >> 4, h = bh & 15;
    const int tid = threadIdx.x;
    const float bias = bfv[h];
    float v[8];
    float s = 0.f;
#pragma unroll
    for (int i = 0; i < 8; ++i) {
        int t = tid * 8 + i;
        float z = glog[(size_t)(b * 2048 + t) * 128 + 48 + h] + bias;
        float lf = (z >= 0.f) ? -log1pf(__expf(-z)) : (z - log1pf(__expf(z)));
        s += lf;
        v[i] = s;
    }
    sums[tid] = s;
    __syncthreads();
    for (int off = 1; off < 256; off <<= 1) {
        float t = (tid >= off) ? sums[tid - off] : 0.f;
        __syncthreads();
        sums[tid] += t;
        __syncthreads();
    }
    float basep = sums[tid] - s;
#pragma unroll
    for (int i = 0; i < 8; ++i)
        cum[(size_t)bh * 2048 + tid * 8 + i] = basep + v[i];
}

// ---------------------------------------------------------------------------
template <bool ROPE>
__global__ void shift_rope(const unsigned short* __restrict__ Y, int ldY, int yoff,
                           const float* __restrict__ glog, int gcol,
                           unsigned short* __restrict__ Out) {
    int gid = blockIdx.x * 256 + threadIdx.x;
    int j = gid & 7;
    int h = (gid >> 3) & 15;
    int t = (gid >> 7) & 2047;
    int b = gid >> 18;
    const unsigned short* yp = Y + (size_t)(b * 2048 + t) * ldY + yoff + h * 128;
    float z  = glog[(size_t)(b * 2048 + t) * 128 + gcol + h];
    float pg = 1.f / (1.f + __expf(-z));
    shortx8 a1 = *(const shortx8*)(yp + j * 8);
    shortx8 a2 = *(const shortx8*)(yp + 64 + j * 8);
    shortx8 b1 = (shortx8){0,0,0,0,0,0,0,0}, b2 = b1;
    if (t > 0) {
        b1 = *(const shortx8*)(yp - ldY + j * 8);
        b2 = *(const shortx8*)(yp - ldY + 64 + j * 8);
    }
    shortx8 o1, o2;
    const float kf = 13.287712379549449f / 64.f;  // log2(10000)/64
#pragma unroll
    for (int i = 0; i < 8; ++i) {
        float m1 = bf2f((unsigned short)a1[i]) * (1.f - pg) + bf2f((unsigned short)b1[i]) * pg;
        float m2 = bf2f((unsigned short)a2[i]) * (1.f - pg) + bf2f((unsigned short)b2[i]) * pg;
        float r1, r2;
        if (ROPE) {
            int d = j * 8 + i;
            float inv = exp2f(-(float)d * kf);
            float ang = (float)t * inv;
            float sv, cv;
            sincosf(ang, &sv, &cv);
            r1 =  m1 * cv + m2 * sv;
            r2 = -m1 * sv + m2 * cv;
        } else { r1 = m1; r2 = m2; }
        o1[i] = (short)f2bf(r1);
        o2[i] = (short)f2bf(r2);
    }
    unsigned short* op = Out + (size_t)((b * 16 + h) * 2048 + t) * 128;
    *(shortx8*)(op + j * 8)      = o1;
    *(shortx8*)(op + 64 + j * 8) = o2;
}

// (BH,T,D) -> (BH,D,T) bf16 transpose
__global__ void transpose_v(const unsigned short* __restrict__ V, unsigned short* __restrict__ Vt) {
    __shared__ unsigned short tile[32][33];
    const int bh = blockIdx.z;
    const int t0 = blockIdx.x * 32, d0 = blockIdx.y * 32;
    const int tx = threadIdx.x, ty = threadIdx.y;
#pragma unroll
    for (int i = 0; i < 4; ++i) {
        int row = ty + i * 8;
        tile[row][tx] = V[(size_t)(bh * 2048 + t0 + row) * 128 + d0 + tx];
    }
    __syncthreads();
#pragma unroll
    for (int i = 0; i < 4; ++i) {
        int drow = ty + i * 8;
        Vt[(size_t)(bh * 128 + d0 + drow) * 2048 + t0 + tx] = tile[tx][drow];
    }
}

// ---------------------------------------------------------------------------
// flash v3: QBLK=128 (8 waves x 16 q-rows), KVBLK=32.  Counted-vmcnt depth-2
// pipeline: 3 K/V LDS buffers; per tile {vmcnt(2); s_barrier; issue tile kt+2;
// compute tile kt}.  cum row staged to LDS so the loop body's only VMEM ops
// are the 2 DMAs -> vmcnt counting is exact (any in-loop VGPR global load
// would force in-order drain of younger DMAs and serialize the pipeline).
// Race audit: buf b=kt%3 is read at compute(kt); next write is the DMA issued
// at iter kt+1 AFTER barrier(kt+1), which no wave passes until all finished
// compute(kt).  Tile-kt data ready: each thread waits own vmcnt(2) (tile kt
// is oldest outstanding), then barrier -> all threads' DMAs landed.
// ---------------------------------------------------------------------------
__global__ __launch_bounds__(512)
void flash_fwd(const unsigned short* __restrict__ Q, const unsigned short* __restrict__ Km,
               const unsigned short* __restrict__ Vt, const float* __restrict__ cum,
               unsigned short* __restrict__ O) {
    __shared__ __align__(16) unsigned short Ks[3][32 * 128];   // 24 KB
    __shared__ __align__(16) unsigned short Vs[3][64 * 64];    // 24 KB (packed V)
    __shared__ __align__(16) float          cumLds[2048];      //  8 KB
    __shared__ __align__(16) unsigned short Plds[8][16][40];   // 10 KB per-wave P slab
    const int tid = threadIdx.x, lane = tid & 63, w = tid >> 6;
    const int l15 = lane & 15, lg = lane >> 4;
    const int bh = blockIdx.y, b = bh >> 4, h = bh & 15;
    const int qx = (blockIdx.x + bh) & 15;         // diagonal remap: balance causal depth
    const int q0 = qx * 128;
    const int qr = q0 + w * 16;
    const size_t base = (size_t)bh * (2048 * 128);
    const float isd = 0.08838834764831845f;        // 1/sqrt(128)
    const int ntiles = 4 * qx + 4;                 // >= 4 always
    const int myn0 = ((qr + 15) >> 5) + 1;
    const int myn = myn0 < ntiles ? myn0 : ntiles; // this wave's causal frontier

    // staging (chunk = 16B): LDS[r][c] <- G[r][c ^ (r&7)]  (both-sides involution)
    const int ik = w * 64 + lane;
    const int kr = ik >> 4, kc = ik & 15;
    const unsigned short* ksrc = Km + base + (size_t)kr * 128 + ((kc ^ (kr & 7)) * 8);
    const int vr = ik >> 3, vc = ik & 7;
    const int vcc = vc ^ (vr & 7);
    const unsigned short* vsrc = Vt + (size_t)(bh * 128 + 2 * vr + (vcc >> 2)) * 2048 + (vcc & 3) * 8;

    const int kx = l15 & 7;                        // K-frag row-xor (read side)
    const int vconst = ((l15 >> 1) * 64) + ((((l15 & 1) * 4 + lg) ^ ((l15 >> 1) & 7)) * 8);

    // ---- prologue: VGPR loads FIRST (so their waits never force DMA drains) ----
    shortx8 aq[4];
#pragma unroll
    for (int kk = 0; kk < 4; ++kk)
        aq[kk] = *(const shortx8*)(Q + base + (size_t)(qr + l15) * 128 + kk * 32 + 8 * lg);
    float cum_t[4];
#pragma unroll
    for (int r = 0; r < 4; ++r) cum_t[r] = cum[bh * 2048 + qr + 4 * lg + r];

    // DMAs: cum row, then tiles 0 and 1 (5 ops; iter-0 vmcnt(2) drains cum+tile0)
    async16(&cumLds[ik * 4], cum + (size_t)bh * 2048 + ik * 4);
    async16(&Ks[0][ik * 8], ksrc);
    async16(&Vs[0][ik * 8], vsrc);
    async16(&Ks[1][ik * 8], ksrc + 32 * 128);
    async16(&Vs[1][ik * 8], vsrc + 32);

    floatx4 oacc[8];
#pragma unroll
    for (int d = 0; d < 8; ++d) oacc[d] = (floatx4){0.f, 0.f, 0.f, 0.f};
    float m[4]  = {-1e30f, -1e30f, -1e30f, -1e30f};
    float ls[4] = {0.f, 0.f, 0.f, 0.f};

    int bc = 0, bi = 2;
    for (int kt = 0; kt < ntiles; ++kt) {
        asm volatile("s_waitcnt vmcnt(2)" ::: "memory");   // tile kt landed (never 0: T4)
        __builtin_amdgcn_s_barrier();
        if (kt + 2 < ntiles) {                     // prefetch depth 2
            async16(&Ks[bi][ik * 8], ksrc + (size_t)(kt + 2) * 32 * 128);
            async16(&Vs[bi][ik * 8], vsrc + (kt + 2) * 32);
        }
        if (kt < myn) {                            // wave-uniform causal skip
            const int s0 = kt * 32;
            floatx4 sacc[2];
            sacc[0] = (floatx4){0.f, 0.f, 0.f, 0.f};
            sacc[1] = (floatx4){0.f, 0.f, 0.f, 0.f};
#pragma unroll
            for (int sf = 0; sf < 2; ++sf)
#pragma unroll
                for (int kk = 0; kk < 4; ++kk) {
                    shortx8 bk = *(const shortx8*)&Ks[bc][(sf * 16 + l15) * 128 + (((kk * 4 + lg) ^ kx) * 8)];
                    sacc[sf] = __builtin_amdgcn_mfma_f32_16x16x32_bf16(aq[kk], bk, sacc[sf], 0, 0, 0);
                }
            float cs[2];
#pragma unroll
            for (int sf = 0; sf < 2; ++sf) cs[sf] = cumLds[s0 + sf * 16 + l15];

            float p[2][4];
            float tmax[4] = {-1e30f, -1e30f, -1e30f, -1e30f};
            const bool maskt = (s0 + 31 > qr);
#pragma unroll
            for (int sf = 0; sf < 2; ++sf)
#pragma unroll
                for (int r = 0; r < 4; ++r) {
                    float sv = sacc[sf][r] * isd + cum_t[r] - cs[sf];
                    if (maskt) {
                        int trow = qr + 4 * lg + r;
                        int scol = s0 + sf * 16 + l15;
                        if (scol > trow) sv = -1e30f;
                    }
                    p[sf][r] = sv;
                    tmax[r] = fmaxf(tmax[r], sv);
                }
#pragma unroll
            for (int r = 0; r < 4; ++r) {
                tmax[r] = fmaxf(tmax[r], __shfl_xor(tmax[r], 1));
                tmax[r] = fmaxf(tmax[r], __shfl_xor(tmax[r], 2));
                tmax[r] = fmaxf(tmax[r], __shfl_xor(tmax[r], 4));
                tmax[r] = fmaxf(tmax[r], __shfl_xor(tmax[r], 8));
            }
            // T13 defer-rescale: skip O-rescale while max growth <= 8 (e^8 headroom, fp32)
            float g = tmax[0] - m[0];
            g = fmaxf(g, tmax[1] - m[1]);
            g = fmaxf(g, tmax[2] - m[2]);
            g = fmaxf(g, tmax[3] - m[3]);
            if (!__all(g <= 8.0f)) {
                float scl[4];
#pragma unroll
                for (int r = 0; r < 4; ++r) {
                    float mn = fmaxf(m[r], tmax[r]);
                    scl[r] = __expf(m[r] - mn);
                    m[r] = mn;
                    ls[r] *= scl[r];
                }
#pragma unroll
                for (int d = 0; d < 8; ++d)
#pragma unroll
                    for (int r = 0; r < 4; ++r) oacc[d][r] *= scl[r];
            }
            float rs[4] = {0.f, 0.f, 0.f, 0.f};
#pragma unroll
            for (int sf = 0; sf < 2; ++sf)
#pragma unroll
                for (int r = 0; r < 4; ++r) {
                    float e = __expf(p[sf][r] - m[r]);
                    p[sf][r] = e;
                    rs[r] += e;
                }
#pragma unroll
            for (int r = 0; r < 4; ++r) {
                rs[r] += __shfl_xor(rs[r], 1);
                rs[r] += __shfl_xor(rs[r], 2);
                rs[r] += __shfl_xor(rs[r], 4);
                rs[r] += __shfl_xor(rs[r], 8);
                ls[r] += rs[r];
            }
            // P: D-layout -> per-wave LDS slab -> A-layout (in-order DS within wave)
#pragma unroll
            for (int sf = 0; sf < 2; ++sf)
#pragma unroll
                for (int r = 0; r < 4; ++r)
                    Plds[w][4 * lg + r][sf * 16 + l15] = f2bf(p[sf][r]);
            shortx8 pa = *(const shortx8*)&Plds[w][l15][8 * lg];
#pragma unroll
            for (int d = 0; d < 8; ++d) {
                shortx8 bv = *(const shortx8*)&Vs[bc][d * 512 + vconst];
                oacc[d] = __builtin_amdgcn_mfma_f32_16x16x32_bf16(pa, bv, oacc[d], 0, 0, 0);
            }
        }
        bc = (bc == 2) ? 0 : bc + 1;
        bi = (bi == 2) ? 0 : bi + 1;
    }
#pragma unroll
    for (int r = 0; r < 4; ++r) {
        float inv = 1.f / ls[r];
        int trow = qr + 4 * lg + r;
        size_t ob = (size_t)(b * 2048 + trow) * 2048 + h * 128;
#pragma unroll
        for (int d = 0; d < 8; ++d)
            O[ob + d * 16 + l15] = f2bf(oacc[d][r] * inv);
    }
}

// ---------------------------------------------------------------------------
extern "C" void kernel_launch(void* const* d_in, const int* in_sizes, int n_in,
                              void* d_out, int out_size, void* d_ws, size_t ws_size,
                              hipStream_t stream) {
    const float* x   = (const float*)d_in[0];
    const float* Wq  = (const float*)d_in[1];
    const float* Wsq = (const float*)d_in[2];
    const float* Wk  = (const float*)d_in[3];
    const float* Wsk = (const float*)d_in[4];
    const float* Wv  = (const float*)d_in[5];
    const float* Wsv = (const float*)d_in[6];
    const float* Wf  = (const float*)d_in[7];
    const float* bfv = (const float*)d_in[8];
    const float* Wo  = (const float*)d_in[9];
    float* out = (float*)d_out;
    char* ws = (char*)d_ws;

    if (ws_size >= 145489920ull) {
        // ---- fused-QKV path (138.8 MB) ----
        unsigned short* xb    = (unsigned short*)(ws + 0);           // 16 MB; later: flash out
        unsigned short* Wb3   = (unsigned short*)(ws + 16777216);    // 24 MB  Wq|Wk|Wv bf16; later Wo
        unsigned short* wcat  = (unsigned short*)(ws + 41943040);    // 0.5 MB
        float*          glog  = (float*)(ws + 42467328);             // 2 MB
        float*          cum   = (float*)(ws + 44564480);             // .25 MB
        unsigned short* qbuf  = (unsigned short*)(ws + 44826624);    // 16 MB
        unsigned short* kbuf  = (unsigned short*)(ws + 61603840);    // 16 MB
        unsigned short* vbuf  = (unsigned short*)(ws + 78381056);    // 16 MB
        unsigned short* ybuf3 = (unsigned short*)(ws + 95158272);    // 48 MB (4096,6144)
        unsigned short* vt    = ybuf3;                               // reuse after shifts

        cvt_bf16<<<4096, 256, 0, stream>>>(x, xb, 1048576);
        build_wcat<<<128, 256, 0, stream>>>(Wsq, Wsk, Wsv, Wf, wcat);
        gemm_bt<float><<<dim3(32, 1), 256, 0, stream>>>(xb, wcat, glog, 4096, 128, 2048);
        cumsum_logf<<<32, 256, 0, stream>>>(glog, bfv, cum);

        cvt_bf16<<<2048, 256, 0, stream>>>(Wq, Wb3, 524288);
        cvt_bf16<<<2048, 256, 0, stream>>>(Wk, Wb3 + 4194304, 524288);
        cvt_bf16<<<2048, 256, 0, stream>>>(Wv, Wb3 + 8388608, 524288);
        gemm_bt<unsigned short><<<dim3(32, 48), 256, 0, stream>>>(xb, Wb3, ybuf3, 4096, 6144, 2048);

        shift_rope<true><<<2048, 256, 0, stream>>>(ybuf3, 6144, 0, glog, 0, qbuf);
        shift_rope<true><<<2048, 256, 0, stream>>>(ybuf3, 6144, 2048, glog, 16, kbuf);
        shift_rope<false><<<2048, 256, 0, stream>>>(ybuf3, 6144, 4096, glog, 32, vbuf);
        transpose_v<<<dim3(64, 4, 32), dim3(32, 8), 0, stream>>>(vbuf, vt);

        flash_fwd<<<dim3(16, 32), 512, 0, stream>>>(qbuf, kbuf, vt, cum, xb);

        cvt_bf16<<<2048, 256, 0, stream>>>(Wo, Wb3, 524288);
        gemm_bt<float><<<dim3(32, 16), 256, 0, stream>>>(xb, Wb3, out, 4096, 2048, 2048);
    } else {
        // ---- fallback (107 MB) ----
        unsigned short* xb   = (unsigned short*)(ws + 0);
        unsigned short* Wb   = (unsigned short*)(ws + 16777216);
        unsigned short* wcat = (unsigned short*)(ws + 25165824);
        float*          glog = (float*)(ws + 25690112);
        float*          cum  = (float*)(ws + 27787264);
        unsigned short* ybuf = (unsigned short*)(ws + 28049408);
        unsigned short* qbuf = (unsigned short*)(ws + 44826624);
        unsigned short* kbuf = (unsigned short*)(ws + 61603840);
        unsigned short* vbuf = (unsigned short*)(ws + 78381056);
        unsigned short* vt   = (unsigned short*)(ws + 95158272);

        cvt_bf16<<<4096, 256, 0, stream>>>(x, xb, 1048576);
        build_wcat<<<128, 256, 0, stream>>>(Wsq, Wsk, Wsv, Wf, wcat);
        gemm_bt<float><<<dim3(32, 1), 256, 0, stream>>>(xb, wcat, glog, 4096, 128, 2048);
        cumsum_logf<<<32, 256, 0, stream>>>(glog, bfv, cum);

        cvt_bf16<<<2048, 256, 0, stream>>>(Wq, Wb, 524288);
        gemm_bt<unsigned short><<<dim3(32, 16), 256, 0, stream>>>(xb, Wb, ybuf, 4096, 2048, 2048);
        shift_rope<true><<<2048, 256, 0, stream>>>(ybuf, 2048, 0, glog, 0, qbuf);

        cvt_bf16<<<2048, 256, 0, stream>>>(Wk, Wb, 524288);
        gemm_bt<unsigned short><<<dim3(32, 16), 256, 0, stream>>>(xb, Wb, ybuf, 4096, 2048, 2048);
        shift_rope<true><<<2048, 256, 0, stream>>>(ybuf, 2048, 0, glog, 16, kbuf);

        cvt_bf16<<<2048, 256, 0, stream>>>(Wv, Wb, 524288);
        gemm_bt<unsigned short><<<dim3(32, 16), 256, 0, stream>>>(xb, Wb, ybuf, 4096, 2048, 2048);
        shift_rope<false><<<2048, 256, 0, stream>>>(ybuf, 2048, 0, glog, 32, vbuf);
        transpose_v<<<dim3(64, 4, 32), dim3(32, 8), 0, stream>>>(vbuf, vt);

        flash_fwd<<<dim3(16, 32), 512, 0, stream>>>(qbuf, kbuf, vt, cum, ybuf);

        cvt_bf16<<<2048, 256, 0, stream>>>(Wo, Wb, 524288);
        gemm_bt<float><<<dim3(32, 16), 256, 0, stream>>>(ybuf, Wb, out, 4096, 2048, 2048);
    }
}

// Round 6
// 495.866 us; speedup vs baseline: 1.1909x; 1.1909x over previous
//
#include <hip/hip_runtime.h>
#include <math.h>

// ---------------------------------------------------------------------------
// ForgettingAttentionLayer, MI355X bf16-MFMA pipeline.  B=2 T=2048 C=2048 H=16 D=128.
// R5: flash v4 = decay-window tile skipping (rigorous Cauchy-Schwarz bound:
//     skipped entries have softmax weight <= e^-30), per-(b,h) |k|max via
//     atomicMax in shift_rope(K), |q|max from frags in-kernel; last-iter
//     vmcnt(0) race fix; diagonal remap dropped (window makes work uniform).
//     RoPE sincos moved to a precomputed table (8.4M -> 131k sincosf).
// ---------------------------------------------------------------------------

typedef __attribute__((ext_vector_type(8))) short  shortx8;
typedef __attribute__((ext_vector_type(4))) float  floatx4;

#define DEV __device__ __forceinline__

DEV unsigned short f2bf(float f) {                 // fp32 -> bf16 RNE
    unsigned int u = __builtin_bit_cast(unsigned int, f);
    u += 0x7FFFu + ((u >> 16) & 1u);
    return (unsigned short)(u >> 16);
}
DEV float bf2f(unsigned short s) {
    unsigned int u = ((unsigned int)s) << 16;
    return __builtin_bit_cast(float, u);
}
DEV void async16(void* lds, const void* g) {       // 16B global->LDS DMA
    __builtin_amdgcn_global_load_lds(
        (const __attribute__((address_space(1))) unsigned int*)g,
        (__attribute__((address_space(3))) unsigned int*)lds, 16, 0, 0);
}

// ---------------------------------------------------------------------------
__global__ void cvt_bf16(const float* __restrict__ in, unsigned short* __restrict__ out, int n8) {
    int i = blockIdx.x * 256 + threadIdx.x;
    if (i >= n8) return;
    float4 u = ((const float4*)in)[2 * i];
    float4 v = ((const float4*)in)[2 * i + 1];
    shortx8 r;
    r[0] = (short)f2bf(u.x); r[1] = (short)f2bf(u.y); r[2] = (short)f2bf(u.z); r[3] = (short)f2bf(u.w);
    r[4] = (short)f2bf(v.x); r[5] = (short)f2bf(v.y); r[6] = (short)f2bf(v.z); r[7] = (short)f2bf(v.w);
    *(shortx8*)(out + (size_t)i * 8) = r;
}

// rope table: tab[t*64+d] = {cos(t*inv_d), sin(t*inv_d)}, inv_d = 10000^(-d/64).
// Also zero-inits kmax[0..31] (atomicMax target, written later by shift_rope).
__global__ void rope_tab(float2* __restrict__ tab, float* __restrict__ kmaxp) {
    int i = blockIdx.x * 256 + threadIdx.x;        // 131072 = 2048*64
    if (i < 32) kmaxp[i] = 0.f;
    int d = i & 63, t = i >> 6;
    float inv = exp2f(-(float)d * (13.287712379549449f / 64.f));
    float sv, cv;
    sincosf((float)t * inv, &sv, &cv);
    tab[i] = make_float2(cv, sv);
}

// Wcat: rows 0-15 Wsq, 16-31 Wsk, 32-47 Wsv, 48-63 Wf, 64-127 zero. (128,2048) bf16
__global__ void build_wcat(const float* __restrict__ Wsq, const float* __restrict__ Wsk,
                           const float* __restrict__ Wsv, const float* __restrict__ Wf,
                           unsigned short* __restrict__ out) {
    int i = blockIdx.x * 256 + threadIdx.x;
    int c8 = i & 255;
    int row = i >> 8;
    const float* src = nullptr;
    if      (row < 16) src = Wsq + (size_t)row * 2048;
    else if (row < 32) src = Wsk + (size_t)(row - 16) * 2048;
    else if (row < 48) src = Wsv + (size_t)(row - 32) * 2048;
    else if (row < 64) src = Wf  + (size_t)(row - 48) * 2048;
    shortx8 r = (shortx8){0,0,0,0,0,0,0,0};
    if (src) {
#pragma unroll
        for (int q = 0; q < 8; ++q) r[q] = (short)f2bf(src[c8 * 8 + q]);
    }
    *(shortx8*)(out + (size_t)i * 8) = r;
}

// ---------------------------------------------------------------------------
// C(M,N) = A(M,K) @ B(N,K)^T ; m97 structure + XCD-aware block swizzle (T1).
// ---------------------------------------------------------------------------
template <typename OutT>
__global__ __launch_bounds__(256)
void gemm_bt(const unsigned short* __restrict__ A, const unsigned short* __restrict__ B,
             OutT* __restrict__ C, int M, int N, int K) {
    __shared__ __align__(16) unsigned short As[2][128 * 32];
    __shared__ __align__(16) unsigned short Bs[2][128 * 32];
    const int tid  = threadIdx.x;
    const int lane = tid & 63;
    const int w    = tid >> 6;
    const int nwg  = gridDim.x * gridDim.y;
    const int bid0 = blockIdx.y * gridDim.x + blockIdx.x;
    const int bids = (bid0 & 7) * (nwg >> 3) + (bid0 >> 3);
    const int m0   = (bids % gridDim.x) * 128;
    const int n0   = (bids / gridDim.x) * 128;
    const int wr   = (w >> 1) * 64;
    const int wc   = (w & 1) * 64;
    const int l15  = lane & 15, lg = lane >> 4;
    const int nk   = K >> 5;
    const int c0   = w * 64 + lane;

    floatx4 acc[4][4];
#pragma unroll
    for (int i = 0; i < 4; ++i)
#pragma unroll
        for (int j = 0; j < 4; ++j) acc[i][j] = (floatx4){0.f, 0.f, 0.f, 0.f};

#pragma unroll
    for (int t = 0; t < 2; ++t) {
        int c = t * 256 + c0;
        int row = c >> 2, seg = c & 3;
        async16(&As[0][(t * 256 + w * 64) * 8], A + (size_t)(m0 + row) * K + seg * 8);
        async16(&Bs[0][(t * 256 + w * 64) * 8], B + (size_t)(n0 + row) * K + seg * 8);
    }
    int cur = 0;
    for (int kt = 0; kt < nk; ++kt) {
        __syncthreads();
        if (kt + 1 < nk) {
#pragma unroll
            for (int t = 0; t < 2; ++t) {
                int c = t * 256 + c0;
                int row = c >> 2, seg = c & 3;
                async16(&As[cur ^ 1][(t * 256 + w * 64) * 8],
                        A + (size_t)(m0 + row) * K + (kt + 1) * 32 + seg * 8);
                async16(&Bs[cur ^ 1][(t * 256 + w * 64) * 8],
                        B + (size_t)(n0 + row) * K + (kt + 1) * 32 + seg * 8);
            }
        }
        shortx8 af[4], bfr[4];
#pragma unroll
        for (int i = 0; i < 4; ++i) {
            af[i]  = *(const shortx8*)&As[cur][(wr + i * 16 + l15) * 32 + 8 * lg];
            bfr[i] = *(const shortx8*)&Bs[cur][(wc + i * 16 + l15) * 32 + 8 * lg];
        }
#pragma unroll
        for (int i = 0; i < 4; ++i)
#pragma unroll
            for (int j = 0; j < 4; ++j)
                acc[i][j] = __builtin_amdgcn_mfma_f32_16x16x32_bf16(af[i], bfr[j], acc[i][j], 0, 0, 0);
        cur ^= 1;
    }
#pragma unroll
    for (int i = 0; i < 4; ++i)
#pragma unroll
        for (int j = 0; j < 4; ++j)
#pragma unroll
            for (int r = 0; r < 4; ++r) {
                int row = m0 + wr + i * 16 + 4 * lg + r;
                int col = n0 + wc + j * 16 + l15;
                float v = acc[i][j][r];
                if constexpr (sizeof(OutT) == 2) C[(size_t)row * N + col] = (OutT)f2bf(v);
                else                             C[(size_t)row * N + col] = v;
            }
}

// ---------------------------------------------------------------------------
__global__ void cumsum_logf(const float* __restrict__ glog, const float* __restrict__ bfv,
                            float* __restrict__ cum) {
    __shared__ float sums[256];
    const int bh = blockIdx.x, b = bh >> 4, h = bh & 15;
    const int tid = threadIdx.x;
    const float bias = bfv[h];
    float v[8];
    float s = 0.f;
#pragma unroll
    for (int i = 0; i < 8; ++i) {
        int t = tid * 8 + i;
        float z = glog[(size_t)(b * 2048 + t) * 128 + 48 + h] + bias;
        float lf = (z >= 0.f) ? -log1pf(__expf(-z)) : (z - log1pf(__expf(z)));
        s += lf;
        v[i] = s;
    }
    sums[tid] = s;
    __syncthreads();
    for (int off = 1; off < 256; off <<= 1) {
        float t = (tid >= off) ? sums[tid - off] : 0.f;
        __syncthreads();
        sums[tid] += t;
        __syncthreads();
    }
    float basep = sums[tid] - s;
#pragma unroll
    for (int i = 0; i < 8; ++i)
        cum[(size_t)bh * 2048 + tid * 8 + i] = basep + v[i];
}

// ---------------------------------------------------------------------------
// shift-mix + optional RoPE (table or inline sincos).  If kmaxp != null, also
// computes per-(b,h) max row |k|^2 (pre-rope == post-rope: rotation preserves
// pair norms) via int-bits atomicMax (values >= 0 so int order == float order).
// ---------------------------------------------------------------------------
template <bool ROPE>
__global__ void shift_rope(const unsigned short* __restrict__ Y, int ldY, int yoff,
                           const float* __restrict__ glog, int gcol,
                           const float4* __restrict__ tab4, float* __restrict__ kmaxp,
                           unsigned short* __restrict__ Out) {
    int gid = blockIdx.x * 256 + threadIdx.x;
    int j = gid & 7;
    int h = (gid >> 3) & 15;
    int t = (gid >> 7) & 2047;
    int b = gid >> 18;
    const unsigned short* yp = Y + (size_t)(b * 2048 + t) * ldY + yoff + h * 128;
    float z  = glog[(size_t)(b * 2048 + t) * 128 + gcol + h];
    float pg = 1.f / (1.f + __expf(-z));
    shortx8 a1 = *(const shortx8*)(yp + j * 8);
    shortx8 a2 = *(const shortx8*)(yp + 64 + j * 8);
    shortx8 b1 = (shortx8){0,0,0,0,0,0,0,0}, b2 = b1;
    if (t > 0) {
        b1 = *(const shortx8*)(yp - ldY + j * 8);
        b2 = *(const shortx8*)(yp - ldY + 64 + j * 8);
    }
    float c_[8], s_[8];
    if (ROPE && tab4) {
        const float4* tp = tab4 + (size_t)t * 32 + j * 4;   // 64 float2 per t
#pragma unroll
        for (int k = 0; k < 4; ++k) {
            float4 v4 = tp[k];
            c_[2 * k] = v4.x; s_[2 * k] = v4.y;
            c_[2 * k + 1] = v4.z; s_[2 * k + 1] = v4.w;
        }
    }
    shortx8 o1, o2;
    float n2 = 0.f;
    const float kf = 13.287712379549449f / 64.f;  // log2(10000)/64
#pragma unroll
    for (int i = 0; i < 8; ++i) {
        float m1 = bf2f((unsigned short)a1[i]) * (1.f - pg) + bf2f((unsigned short)b1[i]) * pg;
        float m2 = bf2f((unsigned short)a2[i]) * (1.f - pg) + bf2f((unsigned short)b2[i]) * pg;
        n2 += m1 * m1 + m2 * m2;
        float r1, r2;
        if (ROPE) {
            float sv, cv;
            if (tab4) { cv = c_[i]; sv = s_[i]; }
            else {
                int d = j * 8 + i;
                float inv = exp2f(-(float)d * kf);
                sincosf((float)t * inv, &sv, &cv);
            }
            r1 =  m1 * cv + m2 * sv;
            r2 = -m1 * sv + m2 * cv;
        } else { r1 = m1; r2 = m2; }
        o1[i] = (short)f2bf(r1);
        o2[i] = (short)f2bf(r2);
    }
    if (kmaxp) {
        n2 += __shfl_xor(n2, 1);
        n2 += __shfl_xor(n2, 2);
        n2 += __shfl_xor(n2, 4);                   // row |k|^2 at all 8 lanes of the row-group
        if (j == 0)
            atomicMax((int*)(kmaxp + (b * 16 + h)), __float_as_int(n2));
    }
    unsigned short* op = Out + (size_t)((b * 16 + h) * 2048 + t) * 128;
    *(shortx8*)(op + j * 8)      = o1;
    *(shortx8*)(op + 64 + j * 8) = o2;
}

// (BH,T,D) -> (BH,D,T) bf16 transpose
__global__ void transpose_v(const unsigned short* __restrict__ V, unsigned short* __restrict__ Vt) {
    __shared__ unsigned short tile[32][33];
    const int bh = blockIdx.z;
    const int t0 = blockIdx.x * 32, d0 = blockIdx.y * 32;
    const int tx = threadIdx.x, ty = threadIdx.y;
#pragma unroll
    for (int i = 0; i < 4; ++i) {
        int row = ty + i * 8;
        tile[row][tx] = V[(size_t)(bh * 2048 + t0 + row) * 128 + d0 + tx];
    }
    __syncthreads();
#pragma unroll
    for (int i = 0; i < 4; ++i) {
        int drow = ty + i * 8;
        Vt[(size_t)(bh * 128 + d0 + drow) * 2048 + t0 + tx] = tile[tx][drow];
    }
}

// ---------------------------------------------------------------------------
// flash v4: QBLK=128 (8 waves x 16 q-rows), KVBLK=32, 3-buffer counted-vmcnt
// pipeline + DECAY WINDOW: skip tile T for the wave iff
//   cum(32T+31) > cum(qr) + 2*qkb + 30,  qkb = |q|max_wave * |k|max_bh / sqrt(D)
// (Cauchy-Schwarz => every skipped entry's softmax weight <= e^-30; m_final >=
// diagonal score >= -qkb).  cum is monotone decreasing => skippable prefix =>
// binary search.  Block stages from min over waves.  Last-iter vmcnt(0) fixes
// the 2-outstanding no-op race.  kmaxp==null => wstart=0 (no windowing).
// ---------------------------------------------------------------------------
__global__ __launch_bounds__(512)
void flash_fwd(const unsigned short* __restrict__ Q, const unsigned short* __restrict__ Km,
               const unsigned short* __restrict__ Vt, const float* __restrict__ cum,
               const float* __restrict__ kmaxp, unsigned short* __restrict__ O) {
    __shared__ __align__(16) unsigned short Ks[3][32 * 128];   // 24 KB
    __shared__ __align__(16) unsigned short Vs[3][64 * 64];    // 24 KB (packed V)
    __shared__ __align__(16) float          cumLds[2048];      //  8 KB
    __shared__ __align__(16) unsigned short Plds[8][16][40];   // 10 KB
    __shared__ int wmin[8];
    const int tid = threadIdx.x, lane = tid & 63, w = tid >> 6;
    const int l15 = lane & 15, lg = lane >> 4;
    const int bh = blockIdx.y, b = bh >> 4, h = bh & 15;
    const int qx = blockIdx.x;
    const int q0 = qx * 128;
    const int qr = q0 + w * 16;
    const size_t base = (size_t)bh * (2048 * 128);
    const float isd = 0.08838834764831845f;        // 1/sqrt(128)
    const int ntiles = 4 * qx + 4;
    const int myn0 = ((qr + 15) >> 5) + 1;
    const int myn = myn0 < ntiles ? myn0 : ntiles; // causal frontier (tiles)

    // staging (chunk = 16B): LDS[r][c] <- G[r][c ^ (r&7)]  (both-sides involution)
    const int ik = w * 64 + lane;
    const int kr = ik >> 4, kc = ik & 15;
    const unsigned short* ksrc = Km + base + (size_t)kr * 128 + ((kc ^ (kr & 7)) * 8);
    const int vr = ik >> 3, vc = ik & 7;
    const int vcc = vc ^ (vr & 7);
    const unsigned short* vsrc = Vt + (size_t)(bh * 128 + 2 * vr + (vcc >> 2)) * 2048 + (vcc & 3) * 8;

    const int kx = l15 & 7;
    const int vconst = ((l15 >> 1) * 64) + ((((l15 & 1) * 4 + lg) ^ ((l15 >> 1) & 7)) * 8);

    // ---- prologue ----
    async16(&cumLds[ik * 4], cum + (size_t)bh * 2048 + ik * 4);
    shortx8 aq[4];
#pragma unroll
    for (int kk = 0; kk < 4; ++kk)
        aq[kk] = *(const shortx8*)(Q + base + (size_t)(qr + l15) * 128 + kk * 32 + 8 * lg);
    float kn2 = kmaxp ? kmaxp[bh] : 0.f;
    asm volatile("s_waitcnt vmcnt(0)" ::: "memory");
    __syncthreads();                               // cumLds visible

    float cum_t[4];
#pragma unroll
    for (int r = 0; r < 4; ++r) cum_t[r] = cumLds[qr + 4 * lg + r];

    int wstart = 0;
    if (kmaxp) {
        float qp = 0.f;
#pragma unroll
        for (int kk = 0; kk < 4; ++kk)
#pragma unroll
            for (int i = 0; i < 8; ++i) {
                float v = bf2f((unsigned short)aq[kk][i]);
                qp += v * v;
            }
        qp += __shfl_xor(qp, 16);
        qp += __shfl_xor(qp, 32);                  // row |q|^2
        float qn2 = qp;
        qn2 = fmaxf(qn2, __shfl_xor(qn2, 1));
        qn2 = fmaxf(qn2, __shfl_xor(qn2, 2));
        qn2 = fmaxf(qn2, __shfl_xor(qn2, 4));
        qn2 = fmaxf(qn2, __shfl_xor(qn2, 8));      // wave max |q|^2
        float qkb = sqrtf(qn2 * kn2) * isd;
        float thr = cumLds[qr] + 2.f * qkb + 30.f;
        int lo = 0, hi = myn - 1;                  // first T with cum[32T+31] <= thr
        while (lo < hi) {
            int mid = (lo + hi) >> 1;
            if (cumLds[32 * mid + 31] > thr) lo = mid + 1; else hi = mid;
        }
        wstart = lo;
    }
    if (lane == 0) wmin[w] = wstart;
    __syncthreads();
    int s0b = wmin[0];
#pragma unroll
    for (int i = 1; i < 8; ++i) s0b = min(s0b, wmin[i]);

    // stage tiles s0b and t2 (duplicate last tile if window is 1 tile wide)
    const int t2 = (s0b + 1 < ntiles) ? s0b + 1 : s0b;
    async16(&Ks[0][ik * 8], ksrc + (size_t)s0b * 32 * 128);
    async16(&Vs[0][ik * 8], vsrc + s0b * 32);
    async16(&Ks[1][ik * 8], ksrc + (size_t)t2 * 32 * 128);
    async16(&Vs[1][ik * 8], vsrc + t2 * 32);

    floatx4 oacc[8];
#pragma unroll
    for (int d = 0; d < 8; ++d) oacc[d] = (floatx4){0.f, 0.f, 0.f, 0.f};
    float m[4]  = {-1e30f, -1e30f, -1e30f, -1e30f};
    float ls[4] = {0.f, 0.f, 0.f, 0.f};

    int bc = 0, bi = 2;
    for (int kt = s0b; kt < ntiles; ++kt) {
        if (kt + 1 < ntiles) { asm volatile("s_waitcnt vmcnt(2)" ::: "memory"); }
        else                 { asm volatile("s_waitcnt vmcnt(0)" ::: "memory"); }  // race fix
        __builtin_amdgcn_s_barrier();
        if (kt + 2 < ntiles) {
            async16(&Ks[bi][ik * 8], ksrc + (size_t)(kt + 2) * 32 * 128);
            async16(&Vs[bi][ik * 8], vsrc + (kt + 2) * 32);
        }
        if (kt >= wstart && kt < myn) {
            const int s0 = kt * 32;
            floatx4 sacc[2];
            sacc[0] = (floatx4){0.f, 0.f, 0.f, 0.f};
            sacc[1] = (floatx4){0.f, 0.f, 0.f, 0.f};
#pragma unroll
            for (int sf = 0; sf < 2; ++sf)
#pragma unroll
                for (int kk = 0; kk < 4; ++kk) {
                    shortx8 bk = *(const shortx8*)&Ks[bc][(sf * 16 + l15) * 128 + (((kk * 4 + lg) ^ kx) * 8)];
                    sacc[sf] = __builtin_amdgcn_mfma_f32_16x16x32_bf16(aq[kk], bk, sacc[sf], 0, 0, 0);
                }
            float cs[2];
#pragma unroll
            for (int sf = 0; sf < 2; ++sf) cs[sf] = cumLds[s0 + sf * 16 + l15];

            float p[2][4];
            float tmax[4] = {-1e30f, -1e30f, -1e30f, -1e30f};
            const bool maskt = (s0 + 31 > qr);
#pragma unroll
            for (int sf = 0; sf < 2; ++sf)
#pragma unroll
                for (int r = 0; r < 4; ++r) {
                    float sv = sacc[sf][r] * isd + cum_t[r] - cs[sf];
                    if (maskt) {
                        int trow = qr + 4 * lg + r;
                        int scol = s0 + sf * 16 + l15;
                        if (scol > trow) sv = -1e30f;
                    }
                    p[sf][r] = sv;
                    tmax[r] = fmaxf(tmax[r], sv);
                }
#pragma unroll
            for (int r = 0; r < 4; ++r) {
                tmax[r] = fmaxf(tmax[r], __shfl_xor(tmax[r], 1));
                tmax[r] = fmaxf(tmax[r], __shfl_xor(tmax[r], 2));
                tmax[r] = fmaxf(tmax[r], __shfl_xor(tmax[r], 4));
                tmax[r] = fmaxf(tmax[r], __shfl_xor(tmax[r], 8));
            }
            float g = tmax[0] - m[0];
            g = fmaxf(g, tmax[1] - m[1]);
            g = fmaxf(g, tmax[2] - m[2]);
            g = fmaxf(g, tmax[3] - m[3]);
            if (!__all(g <= 8.0f)) {               // T13 defer-rescale
                float scl[4];
#pragma unroll
                for (int r = 0; r < 4; ++r) {
                    float mn = fmaxf(m[r], tmax[r]);
                    scl[r] = __expf(m[r] - mn);
                    m[r] = mn;
                    ls[r] *= scl[r];
                }
#pragma unroll
                for (int d = 0; d < 8; ++d)
#pragma unroll
                    for (int r = 0; r < 4; ++r) oacc[d][r] *= scl[r];
            }
            float rs[4] = {0.f, 0.f, 0.f, 0.f};
#pragma unroll
            for (int sf = 0; sf < 2; ++sf)
#pragma unroll
                for (int r = 0; r < 4; ++r) {
                    float e = __expf(p[sf][r] - m[r]);
                    p[sf][r] = e;
                    rs[r] += e;
                }
#pragma unroll
            for (int r = 0; r < 4; ++r) {
                rs[r] += __shfl_xor(rs[r], 1);
                rs[r] += __shfl_xor(rs[r], 2);
                rs[r] += __shfl_xor(rs[r], 4);
                rs[r] += __shfl_xor(rs[r], 8);
                ls[r] += rs[r];
            }
#pragma unroll
            for (int sf = 0; sf < 2; ++sf)
#pragma unroll
                for (int r = 0; r < 4; ++r)
                    Plds[w][4 * lg + r][sf * 16 + l15] = f2bf(p[sf][r]);
            shortx8 pa = *(const shortx8*)&Plds[w][l15][8 * lg];
#pragma unroll
            for (int d = 0; d < 8; ++d) {
                shortx8 bv = *(const shortx8*)&Vs[bc][d * 512 + vconst];
                oacc[d] = __builtin_amdgcn_mfma_f32_16x16x32_bf16(pa, bv, oacc[d], 0, 0, 0);
            }
        }
        bc = (bc == 2) ? 0 : bc + 1;
        bi = (bi == 2) ? 0 : bi + 1;
    }
#pragma unroll
    for (int r = 0; r < 4; ++r) {
        float inv = 1.f / ls[r];
        int trow = qr + 4 * lg + r;
        size_t ob = (size_t)(b * 2048 + trow) * 2048 + h * 128;
#pragma unroll
        for (int d = 0; d < 8; ++d)
            O[ob + d * 16 + l15] = f2bf(oacc[d][r] * inv);
    }
}

// ---------------------------------------------------------------------------
extern "C" void kernel_launch(void* const* d_in, const int* in_sizes, int n_in,
                              void* d_out, int out_size, void* d_ws, size_t ws_size,
                              hipStream_t stream) {
    const float* x   = (const float*)d_in[0];
    const float* Wq  = (const float*)d_in[1];
    const float* Wsq = (const float*)d_in[2];
    const float* Wk  = (const float*)d_in[3];
    const float* Wsk = (const float*)d_in[4];
    const float* Wv  = (const float*)d_in[5];
    const float* Wsv = (const float*)d_in[6];
    const float* Wf  = (const float*)d_in[7];
    const float* bfv = (const float*)d_in[8];
    const float* Wo  = (const float*)d_in[9];
    float* out = (float*)d_out;
    char* ws = (char*)d_ws;

    if (ws_size >= 146538880ull) {
        // ---- fused-QKV + windowed-flash path (139.8 MB) ----
        unsigned short* xb    = (unsigned short*)(ws + 0);           // 16 MB; later: flash out
        unsigned short* Wb3   = (unsigned short*)(ws + 16777216);    // 24 MB
        unsigned short* wcat  = (unsigned short*)(ws + 41943040);    // 0.5 MB
        float*          glog  = (float*)(ws + 42467328);             // 2 MB
        float*          cum   = (float*)(ws + 44564480);             // .25 MB
        unsigned short* qbuf  = (unsigned short*)(ws + 44826624);    // 16 MB
        unsigned short* kbuf  = (unsigned short*)(ws + 61603840);    // 16 MB
        unsigned short* vbuf  = (unsigned short*)(ws + 78381056);    // 16 MB
        float2*         tab   = (float2*)(ws + 95158272);            // 1 MB rope table
        float*          kmaxb = (float*)(ws + 96206848);             // 128 B
        unsigned short* ybuf3 = (unsigned short*)(ws + 96207232);    // 48 MB (4096,6144)
        unsigned short* vt    = ybuf3;                               // reuse after shifts

        cvt_bf16<<<4096, 256, 0, stream>>>(x, xb, 1048576);
        rope_tab<<<512, 256, 0, stream>>>(tab, kmaxb);
        build_wcat<<<128, 256, 0, stream>>>(Wsq, Wsk, Wsv, Wf, wcat);
        gemm_bt<float><<<dim3(32, 1), 256, 0, stream>>>(xb, wcat, glog, 4096, 128, 2048);
        cumsum_logf<<<32, 256, 0, stream>>>(glog, bfv, cum);

        cvt_bf16<<<2048, 256, 0, stream>>>(Wq, Wb3, 524288);
        cvt_bf16<<<2048, 256, 0, stream>>>(Wk, Wb3 + 4194304, 524288);
        cvt_bf16<<<2048, 256, 0, stream>>>(Wv, Wb3 + 8388608, 524288);
        gemm_bt<unsigned short><<<dim3(32, 48), 256, 0, stream>>>(xb, Wb3, ybuf3, 4096, 6144, 2048);

        shift_rope<true><<<2048, 256, 0, stream>>>(ybuf3, 6144, 0,    glog, 0,  (const float4*)tab, nullptr, qbuf);
        shift_rope<true><<<2048, 256, 0, stream>>>(ybuf3, 6144, 2048, glog, 16, (const float4*)tab, kmaxb,  kbuf);
        shift_rope<false><<<2048, 256, 0, stream>>>(ybuf3, 6144, 4096, glog, 32, nullptr, nullptr, vbuf);
        transpose_v<<<dim3(64, 4, 32), dim3(32, 8), 0, stream>>>(vbuf, vt);

        flash_fwd<<<dim3(16, 32), 512, 0, stream>>>(qbuf, kbuf, vt, cum, kmaxb, xb);

        cvt_bf16<<<2048, 256, 0, stream>>>(Wo, Wb3, 524288);
        gemm_bt<float><<<dim3(32, 16), 256, 0, stream>>>(xb, Wb3, out, 4096, 2048, 2048);
    } else {
        // ---- fallback (107 MB): no table, no windowing ----
        unsigned short* xb   = (unsigned short*)(ws + 0);
        unsigned short* Wb   = (unsigned short*)(ws + 16777216);
        unsigned short* wcat = (unsigned short*)(ws + 25165824);
        float*          glog = (float*)(ws + 25690112);
        float*          cum  = (float*)(ws + 27787264);
        unsigned short* ybuf = (unsigned short*)(ws + 28049408);
        unsigned short* qbuf = (unsigned short*)(ws + 44826624);
        unsigned short* kbuf = (unsigned short*)(ws + 61603840);
        unsigned short* vbuf = (unsigned short*)(ws + 78381056);
        unsigned short* vt   = (unsigned short*)(ws + 95158272);

        cvt_bf16<<<4096, 256, 0, stream>>>(x, xb, 1048576);
        build_wcat<<<128, 256, 0, stream>>>(Wsq, Wsk, Wsv, Wf, wcat);
        gemm_bt<float><<<dim3(32, 1), 256, 0, stream>>>(xb, wcat, glog, 4096, 128, 2048);
        cumsum_logf<<<32, 256, 0, stream>>>(glog, bfv, cum);

        cvt_bf16<<<2048, 256, 0, stream>>>(Wq, Wb, 524288);
        gemm_bt<unsigned short><<<dim3(32, 16), 256, 0, stream>>>(xb, Wb, ybuf, 4096, 2048, 2048);
        shift_rope<true><<<2048, 256, 0, stream>>>(ybuf, 2048, 0, glog, 0, nullptr, nullptr, qbuf);

        cvt_bf16<<<2048, 256, 0, stream>>>(Wk, Wb, 524288);
        gemm_bt<unsigned short><<<dim3(32, 16), 256, 0, stream>>>(xb, Wb, ybuf, 4096, 2048, 2048);
        shift_rope<true><<<2048, 256, 0, stream>>>(ybuf, 2048, 0, glog, 16, nullptr, nullptr, kbuf);

        cvt_bf16<<<2048, 256, 0, stream>>>(Wv, Wb, 524288);
        gemm_bt<unsigned short><<<dim3(32, 16), 256, 0, stream>>>(xb, Wb, ybuf, 4096, 2048, 2048);
        shift_rope<false><<<2048, 256, 0, stream>>>(ybuf, 2048, 0, glog, 32, nullptr, nullptr, vbuf);
        transpose_v<<<dim3(64, 4, 32), dim3(32, 8), 0, stream>>>(vbuf, vt);

        flash_fwd<<<dim3(16, 32), 512, 0, stream>>>(qbuf, kbuf, vt, cum, nullptr, ybuf);

        cvt_bf16<<<2048, 256, 0, stream>>>(Wo, Wb, 524288);
        gemm_bt<float><<<dim3(32, 16), 256, 0, stream>>>(ybuf, Wb, out, 4096, 2048, 2048);
    }
}